// Round 13
// baseline (3513.500 us; speedup 1.0000x reference)
//
#include <hip/hip_runtime.h>
#include <hip/hip_fp16.h>

// Decoder: 2-layer LSTM (H=256), T=512, B=256, scalar output feedback.
// Round 16: NB=2 on the i4s8 skeleton. R12 balance: VALU 5.7K (dots only
// ~4K), port 5.4K (weights), serial ~2.2K. Weights are SHARED by both batch
// elements, so NB=2 doubles only the cheap sdot8 path (+4K) while port and
// serial stay flat: ~16K cyc for 2 elems = ~8K/elem vs 13.3K. (R8's NB=2
// failed because its u8-decode dot path was 11K/elem -- that tax is gone.)
//  - h nibble planes fused to one uint4/bigwin (lo||hi): LDS h-broadcast
//    reads halve (1 ds_read_b128) -- R8's doubled-broadcast cost addressed.
//  - branch-free tanh_fast = copysign((1-e)/(1+e), x), e=exp(-2|x|): no
//    libm branches; used for g-gate and tanh(c) (NL count doubles at NB=2).
//  - Keeps: signed-i4 weights (scale max/7) + sdot8 (R12), exact 2-plane
//    i8 h split (scale 1/119), merged phase1 (whh0-LDS dots hide w1h
//    stream), whole whh0 in 128KB LDS (1 block/CU), LICM fence, dual
//    redundant per-wave reduces (R8), fp32 pred/loss path.

namespace {

constexpr int kB = 256, kT = 512, kH = 256;
constexpr int kBW = 16;                     // big-windows of 16 k per matrix
constexpr int kU2PerMat = kBW * 1024;       // 16384 uint2 per matrix (i4)
constexpr size_t kWsNeeded =
    3 * (size_t)kU2PerMat * 8 + 3 * 1024 * 4;  // 393216 + 12288 = 405504

__device__ __forceinline__ float fsig(float v) { return 1.0f / (1.0f + __expf(-v)); }

// Branch-free tanh: e = exp(-2|x|) in (0,1], t = (1-e)/(1+e), sign restored.
__device__ __forceinline__ float tanh_fast(float x) {
  float e = __expf(-2.0f * fabsf(x));
  float t = (1.0f - e) / (1.0f + e);
  return copysignf(t, x);
}

// 8-wide signed i4 dot-accumulate (i32).
__device__ __forceinline__ int sdot8i(uint a, uint b, int c) {
#if __has_builtin(__builtin_amdgcn_sdot8)
  return __builtin_amdgcn_sdot8((int)a, (int)b, c, false);
#else
#pragma unroll
  for (int i = 0; i < 8; ++i) {
    int av = ((int)(a << (28 - 4 * i))) >> 28;
    int bv = ((int)(b << (28 - 4 * i))) >> 28;
    c += av * bv;
  }
  return c;
#endif
}

// One bigwin (16 k) vs fused h planes {lo0,lo1,hi0,hi1}: Dl/Dh accumulate.
__device__ __forceinline__ void dotp(uint2 w, uint4 h, int& Dl, int& Dh) {
  Dl = sdot8i(w.x, h.x, Dl);
  Dl = sdot8i(w.y, h.y, Dl);
  Dh = sdot8i(w.x, h.z, Dh);
  Dh = sdot8i(w.y, h.w, Dh);
}

// Pack this thread's i8 h-quant (|qh|<=119) into the fused plane array.
// hp = uint view of uint4[16]; cell idx in 0..255; 8-lane OR-butterfly,
// leader (idx&7==0) writes lo and hi words.
__device__ __forceinline__ void pack_h(uint* hp, int idx, int qh) {
  int qhi = (qh + 8) >> 4;                  // [-7,7]
  int qlo = qh - (qhi << 4);                // [-8,7], exact: qh = 16*qhi+qlo
  int sh = 4 * (idx & 7);
  uint vlo = (uint)(qlo & 0xF) << sh;
  uint vhi = (uint)(qhi & 0xF) << sh;
  vlo |= __shfl_xor(vlo, 1); vhi |= __shfl_xor(vhi, 1);
  vlo |= __shfl_xor(vlo, 2); vhi |= __shfl_xor(vhi, 2);
  vlo |= __shfl_xor(vlo, 4); vhi |= __shfl_xor(vhi, 4);
  if ((idx & 7) == 0) {
    int g = idx >> 3;                       // word 0..31
    hp[(g >> 1) * 4 + (g & 1)] = vlo;       // .x/.y of uint4[g>>1]
    hp[(g >> 1) * 4 + 2 + (g & 1)] = vhi;   // .z/.w
  }
}

// One wave-row per matrix row: per-row absmax -> scale max/7, quantize to
// SIGNED 2's-complement nibbles. dst u16 layout per matrix:
// [bw(16)][j(1024)][c(4)], u16 c holds nibbles k = 16*bw + 4*c .. +3
// (k ascending, low nibble first). Main loop reads uint2 tile[bw*1024 + j].
__global__ __launch_bounds__(64) void pack_q4s(const float* __restrict__ s0,
                                               const float* __restrict__ s1,
                                               const float* __restrict__ s2,
                                               ushort* __restrict__ dst,
                                               float* __restrict__ scl) {
  int r = blockIdx.x;                 // 0..3071
  int mat = r >> 10, j = r & 1023;
  int ln = threadIdx.x;               // 0..63, covers k = 4*ln..4*ln+3
  const float* src = (mat == 0 ? s0 : (mat == 1 ? s1 : s2)) + j * 256 + ln * 4;
  float4 v = *(const float4*)src;
  float m = fmaxf(fmaxf(fabsf(v.x), fabsf(v.y)), fmaxf(fabsf(v.z), fabsf(v.w)));
#pragma unroll
  for (int off = 32; off > 0; off >>= 1) m = fmaxf(m, __shfl_xor(m, off));
  float rcp = (m > 0.f) ? 7.0f / m : 0.f;
  int q0 = __float2int_rn(v.x * rcp);
  int q1 = __float2int_rn(v.y * rcp);
  int q2 = __float2int_rn(v.z * rcp);
  int q3 = __float2int_rn(v.w * rcp);
  uint p = (uint)(q0 & 0xF) | ((uint)(q1 & 0xF) << 4) |
           ((uint)(q2 & 0xF) << 8) | ((uint)(q3 & 0xF) << 12);
  dst[mat * 65536 + (ln >> 2) * 4096 + j * 4 + (ln & 3)] = (ushort)p;
  if (ln == 0) scl[mat * 1024 + j] = m * (1.0f / 7.0f);
}

__global__ __launch_bounds__(1024) void decoder_i4nb2(
    const float* __restrict__ seq, const float* __restrict__ z,
    const float* __restrict__ wih0, const float* __restrict__ bih0,
    const float* __restrict__ bhh0, const float* __restrict__ bih1,
    const float* __restrict__ bhh1, const float* __restrict__ wout,
    const float* __restrict__ bout, const uint4* __restrict__ w0,
    const uint2* __restrict__ w1i, const uint2* __restrict__ w1h,
    const float* __restrict__ scl, float* __restrict__ loss_out) {
  extern __shared__ uint2 lw[];                   // whole whh0, i4 (128 KB)
  __shared__ alignas(16) uint4 h0p[2][kBW];       // h0 fused nibble planes
  __shared__ alignas(16) uint4 h1p[2][kBW];       // h1 fused nibble planes
  __shared__ float g4[2][1024];
  __shared__ float spred[2][kH];

  const int tid = threadIdx.x;                    // gate row j
  const int b0 = blockIdx.x * 2;                  // batch pair
  const int m = tid >> 8, hr = tid & 255;         // cell role (tid<512)

  // Stage ALL of whh0 (i4) into LDS: 8192 uint4, coalesced.
  {
    uint4* dst4 = (uint4*)lw;
#pragma unroll
    for (int i = 0; i < 8; ++i) dst4[i * 1024 + tid] = w0[i * 1024 + tid];
  }

  float c0 = 0.f, c1 = 0.f, woutr = 0.f, zv = 0.f;
  if (tid < 512) {
    zv = z[(size_t)(b0 + m) * kH + hr];
    c0 = zv;
    c1 = zv;
    woutr = wout[hr];
    spred[m][hr] = fabsf(zv);                     // scratch for init max
  }
  const float wih0_j = wih0[tid];
  const float bias0 = bih0[tid] + bhh0[tid];
  const float bias1 = bih1[tid] + bhh1[tid];
  const float s0j = scl[tid];
  const float s1ij = scl[1024 + tid];
  const float s1hj = scl[2048 + tid];
  const float bo = bout[0];
  const bool isG = (tid >= 512) && (tid < 768);   // wave-uniform (waves 8..11)
  const float r119 = 1.0f / 119.0f;
  float xsA = 0.f, xsB = 0.f, lacc = 0.f;
  __syncthreads();

  // Per-batch max|z| (wave-redundant dual reduce) -> init scales; quantize.
  float sA_init, sB_init;
  {
    int ln = tid & 63;
    float a = fmaxf(fmaxf(spred[0][ln], spred[0][ln + 64]),
                    fmaxf(spred[0][ln + 128], spred[0][ln + 192]));
    float bb = fmaxf(fmaxf(spred[1][ln], spred[1][ln + 64]),
                     fmaxf(spred[1][ln + 128], spred[1][ln + 192]));
#pragma unroll
    for (int off = 32; off > 0; off >>= 1) {
      a = fmaxf(a, __shfl_xor(a, off));
      bb = fmaxf(bb, __shfl_xor(bb, off));
    }
    float mA = fmaxf(a, 1e-20f), mB = fmaxf(bb, 1e-20f);
    sA_init = mA * r119;
    sB_init = mB * r119;
    if (tid < 512) {
      float mm = (m == 0) ? mA : mB;
      int q = __float2int_rn(zv * (119.0f / mm));
      q = max(-119, min(119, q));
      pack_h((uint*)h0p[m], hr, q);
      pack_h((uint*)h1p[m], hr, q);
    }
  }

  const uint2* wpA = w1i + tid;
  const uint2* wpB = w1h + tid;
  const uint2* lwp = lw + tid;
  __syncthreads();

  for (int t = 0; t < kT; ++t) {
    // LICM fence (round-5 post-mortem: hoist->spill->scratch-bound).
    asm volatile("" ::: "memory");
    const float hsA = (t == 0) ? sA_init : r119;  // scale of h written t-1
    const float hsB = (t == 0) ? sB_init : r119;

    // ---- phase 1 (merged): D0 = Whh0.qh0 from LDS (pure VALU)
    //      interleaved with Dh = Whh1.qh1_old streamed (pure port),
    //      both batch elements sharing every weight fetch.
    int D0lA = 0, D0hA = 0, D0lB = 0, D0hB = 0;
    int DhlA = 0, DhhA = 0, DhlB = 0, DhhB = 0;
#pragma unroll 2
    for (int bw = 0; bw < kBW; ++bw) {
      uint2 qB = wpB[(size_t)bw << 10];           // global, dep-free: pipelined
      uint2 wl = lwp[bw << 10];
      dotp(wl, h0p[0][bw], D0lA, D0hA);
      dotp(wl, h0p[1][bw], D0lB, D0hB);
      dotp(qB, h1p[0][bw], DhlA, DhhA);
      dotp(qB, h1p[1][bw], DhlB, DhhB);
    }
    float a0A = fmaf(xsA, wih0_j, bias0) + s0j * hsA * (float)(16 * D0hA + D0lA);
    float a0B = fmaf(xsB, wih0_j, bias0) + s0j * hsB * (float)(16 * D0hB + D0lB);
    if (isG) { g4[0][tid] = tanh_fast(a0A); g4[1][tid] = tanh_fast(a0B); }
    else     { g4[0][tid] = fsig(a0A);      g4[1][tid] = fsig(a0B); }
    __syncthreads();
    if (tid < 512) {
      float gi = g4[m][hr];
      float gf = g4[m][hr + 256];
      float gg = g4[m][hr + 512];
      float go = g4[m][hr + 768];
      c0 = fmaf(gf, c0, gi * gg);
      float hn = go * tanh_fast(c0);              // in (-1,1)
      pack_h((uint*)h0p[m], hr, __float2int_rn(hn * 119.0f));
    }
    __syncthreads();

    // ---- phase 2: Di = Wih1.qh0_new, streamed, both batches ----
    int DilA = 0, DihA = 0, DilB = 0, DihB = 0;
#pragma unroll 2
    for (int bw = 0; bw < kBW; ++bw) {
      uint2 qA = wpA[(size_t)bw << 10];
      dotp(qA, h0p[0][bw], DilA, DihA);
      dotp(qA, h0p[1][bw], DilB, DihB);
    }
    float a1A = bias1 + s1ij * r119 * (float)(16 * DihA + DilA) +
                s1hj * hsA * (float)(16 * DhhA + DhlA);
    float a1B = bias1 + s1ij * r119 * (float)(16 * DihB + DilB) +
                s1hj * hsB * (float)(16 * DhhB + DhlB);
    if (isG) { g4[0][tid] = tanh_fast(a1A); g4[1][tid] = tanh_fast(a1B); }
    else     { g4[0][tid] = fsig(a1A);      g4[1][tid] = fsig(a1B); }
    __syncthreads();
    if (tid < 512) {
      float gi = g4[m][hr];
      float gf = g4[m][hr + 256];
      float gg = g4[m][hr + 512];
      float go = g4[m][hr + 768];
      c1 = fmaf(gf, c1, gi * gg);
      float hn = go * tanh_fast(c1);              // fp32, pre-quantization
      pack_h((uint*)h1p[m], hr, __float2int_rn(hn * 119.0f));
      spred[m][hr] = hn * woutr;                  // pred path stays fp32
    }
    __syncthreads();

    // ---- dual pred reduce (redundant per wave) ----
    {
      int ln = tid & 63;
      float vA = spred[0][ln] + spred[0][ln + 64] + spred[0][ln + 128] +
                 spred[0][ln + 192];
      float vB = spred[1][ln] + spred[1][ln + 64] + spred[1][ln + 128] +
                 spred[1][ln + 192];
#pragma unroll
      for (int off = 32; off > 0; off >>= 1) {
        vA += __shfl_down(vA, off);
        vB += __shfl_down(vB, off);
      }
      float predA = __shfl(vA, 0) + bo;           // broadcast within wave
      float predB = __shfl(vB, 0) + bo;
      xsA = predA;                                // feedback for next step
      xsB = predB;
      if (tid == 0) {
        float dA = seq[(size_t)b0 * kT + t] - predA;
        float dB = seq[(size_t)(b0 + 1) * kT + t] - predB;
        lacc = fmaf(dA, dA, lacc);
        lacc = fmaf(dB, dB, lacc);
      }
    }
    // no barrier needed: next writers pass 2+ barriers first
  }

  if (tid == 0) atomicAdd(loss_out, lacc * (1.0f / ((float)kB * (float)kT)));
}

// ---------------- fallback (reads d_in directly, fp32) ---------------------
__global__ __launch_bounds__(1024) void decoder_fallback(
    const float* __restrict__ seq, const float* __restrict__ z,
    const float* __restrict__ wih0, const float* __restrict__ bih0,
    const float* __restrict__ bhh0, const float* __restrict__ whh0,
    const float* __restrict__ wih1, const float* __restrict__ whh1,
    const float* __restrict__ bih1, const float* __restrict__ bhh1,
    const float* __restrict__ wout, const float* __restrict__ bout,
    float* __restrict__ loss_out) {
  __shared__ float h0s[kH], h1s[kH], g4[1024];
  __shared__ float xs_s;
  const int tid = threadIdx.x;
  const int b = blockIdx.x;
  float c0r = 0.f, c1r = 0.f;
  if (tid < kH) {
    float zv = z[b * kH + tid];
    h0s[tid] = zv; h1s[tid] = zv; c0r = zv; c1r = zv;
  }
  if (tid == 0) xs_s = 0.f;
  const float wih0_j = wih0[tid];
  const float bias0_j = bih0[tid] + bhh0[tid];
  const float bias1_j = bih1[tid] + bhh1[tid];
  const float wout_r = (tid < kH) ? wout[tid] : 0.f;
  const float bo = bout[0];
  float lacc = 0.f;
  __syncthreads();
  for (int t = 0; t < kT; ++t) {
    float a0 = fmaf(xs_s, wih0_j, bias0_j);
    for (int k = 0; k < kH; ++k) a0 = fmaf(whh0[tid * kH + k], h0s[k], a0);
    g4[tid] = a0;
    __syncthreads();
    if (tid < kH) {
      float ig = fsig(g4[tid]), fg = fsig(g4[tid + 256]);
      float gg = tanhf(g4[tid + 512]), og = fsig(g4[tid + 768]);
      c0r = fmaf(fg, c0r, ig * gg);
      h0s[tid] = og * tanhf(c0r);
    }
    __syncthreads();
    float a1 = bias1_j;
    for (int k = 0; k < kH; ++k) a1 = fmaf(wih1[tid * kH + k], h0s[k], a1);
    for (int k = 0; k < kH; ++k) a1 = fmaf(whh1[tid * kH + k], h1s[k], a1);
    g4[tid] = a1;
    __syncthreads();
    if (tid < kH) {
      float ig = fsig(g4[tid]), fg = fsig(g4[tid + 256]);
      float gg = tanhf(g4[tid + 512]), og = fsig(g4[tid + 768]);
      c1r = fmaf(fg, c1r, ig * gg);
      float h1 = og * tanhf(c1r);
      h1s[tid] = h1;
      g4[tid] = h1 * wout_r;
    }
    __syncthreads();
    if (tid < 64) {
      float v = g4[tid] + g4[tid + 64] + g4[tid + 128] + g4[tid + 192];
#pragma unroll
      for (int off = 32; off > 0; off >>= 1) v += __shfl_down(v, off);
      if (tid == 0) {
        float pred = v + bo;
        float d = seq[b * kT + t] - pred;
        lacc = fmaf(d, d, lacc);
        xs_s = pred;
      }
    }
    __syncthreads();
  }
  if (tid == 0) atomicAdd(loss_out, lacc * (1.0f / (float)(kB * kT)));
}

}  // namespace

extern "C" void kernel_launch(void* const* d_in, const int* in_sizes, int n_in,
                              void* d_out, int out_size, void* d_ws, size_t ws_size,
                              hipStream_t stream) {
  const float* seq = (const float*)d_in[0];
  const float* z = (const float*)d_in[1];
  const float* wih0 = (const float*)d_in[3];
  const float* whh0 = (const float*)d_in[4];
  const float* bih0 = (const float*)d_in[5];
  const float* bhh0 = (const float*)d_in[6];
  const float* wih1 = (const float*)d_in[7];
  const float* whh1 = (const float*)d_in[8];
  const float* bih1 = (const float*)d_in[9];
  const float* bhh1 = (const float*)d_in[10];
  const float* wout = (const float*)d_in[11];
  const float* bout = (const float*)d_in[12];
  float* out = (float*)d_out;

  hipMemsetAsync(out, 0, sizeof(float), stream);

  if (ws_size >= kWsNeeded) {
    ushort* wq = (ushort*)d_ws;             // [3][65536] u16 of signed nibbles
    float* scl = (float*)((char*)d_ws + 3 * (size_t)kU2PerMat * 8);
    pack_q4s<<<3072, 64, 0, stream>>>(whh0, wih1, whh1, wq, scl);
    // 128KB dynamic LDS (whole whh0) forces 1 block/CU; 128 blocks, each
    // serving a batch pair from one shared weight stream.
    const uint2* wu = (const uint2*)wq;
    decoder_i4nb2<<<kB / 2, 1024, 128 * 1024, stream>>>(
        seq, z, wih0, bih0, bhh0, bih1, bhh1, wout, bout, (const uint4*)wu,
        wu + kU2PerMat, wu + 2 * kU2PerMat, scl, out);
  } else {
    decoder_fallback<<<kB, 1024, 0, stream>>>(seq, z, wih0, bih0, bhh0, whh0,
                                              wih1, whh1, bih1, bhh1, wout, bout,
                                              out);
  }
}

// Round 14
// 2026.366 us; speedup vs baseline: 1.7339x; 1.7339x over previous
//
#include <hip/hip_runtime.h>
#include <hip/hip_fp16.h>

// Decoder: 2-layer LSTM (H=256), T=512, B=256, scalar output feedback.
// Round 17: revert NB=2 (third failure: R4/R8/R13 -- wall-clock = step-cycles
// of ONE block; idle CUs are not a currency, and dot-VALU doubling always
// exceeds the shared-port saving). Back to R12's NB=1 i4s8 skeleton, plus:
//  - WIDE weight loads: adjacent bigwin PAIRS packed so every streamed load
//    is uint4 (16B/lane, 1024B/wave-instr) instead of uint2 (8B). The
//    47 B/cyc port ceiling was measured at 16B/lane; 8B loads halve the
//    per-instruction return efficiency if the L1 path is instr-limited --
//    this explains R12's residual (VALU 5.7K + port ~8K ~= 13.3K step).
//    Bit-identical numerics (same nibbles, same integer dot order).
//  - Fused h nibble planes (R13-proven layout): one ds_read_b128 per bigwin
//    instead of two b64 -- same width argument on the LDS port.
//  - tanh_fast (R13-proven numerics), whole whh0 in 128KB LDS (1 block/CU),
//    merged phase1 (whh0-LDS dots hide the w1h stream), LICM fence,
//    4-barrier structure (R12-proven), redundant per-wave pred reduce,
//    fp32 pred/loss path.

namespace {

constexpr int kB = 256, kT = 512, kH = 256;
constexpr int kBW = 16;                     // bigwins of 16 k per matrix
constexpr int kBW2 = 8;                     // bigwin PAIRS (32 k) per matrix
constexpr size_t kWsNeeded =
    3 * (size_t)65536 * 2 + 3 * 1024 * 4;   // 393216 + 12288 = 405504

__device__ __forceinline__ float fsig(float v) { return 1.0f / (1.0f + __expf(-v)); }

// Branch-free tanh: e = exp(-2|x|) in (0,1], t = (1-e)/(1+e), sign restored.
__device__ __forceinline__ float tanh_fast(float x) {
  float e = __expf(-2.0f * fabsf(x));
  float t = (1.0f - e) / (1.0f + e);
  return copysignf(t, x);
}

// 8-wide signed i4 dot-accumulate (i32).
__device__ __forceinline__ int sdot8i(uint a, uint b, int c) {
#if __has_builtin(__builtin_amdgcn_sdot8)
  return __builtin_amdgcn_sdot8((int)a, (int)b, c, false);
#else
#pragma unroll
  for (int i = 0; i < 8; ++i) {
    int av = ((int)(a << (28 - 4 * i))) >> 28;
    int bv = ((int)(b << (28 - 4 * i))) >> 28;
    c += av * bv;
  }
  return c;
#endif
}

// One bigwin (16 k, words wx=k0..7 wy=k8..15) vs fused h planes
// {lo0,lo1,hi0,hi1}: accumulate low/high-plane dots.
__device__ __forceinline__ void dotw(uint wx, uint wy, uint4 h, int& Dl,
                                     int& Dh) {
  Dl = sdot8i(wx, h.x, Dl);
  Dl = sdot8i(wy, h.y, Dl);
  Dh = sdot8i(wx, h.z, Dh);
  Dh = sdot8i(wy, h.w, Dh);
}

// Pack this thread's i8 h-quant (|qh|<=119) into the fused plane array.
// hp = uint view of uint4[16]; idx in 0..255; 8-lane OR-butterfly,
// leader (idx&7==0) writes lo and hi words. (R13-proven.)
__device__ __forceinline__ void pack_h(uint* hp, int idx, int qh) {
  int qhi = (qh + 8) >> 4;                  // [-7,7]
  int qlo = qh - (qhi << 4);                // [-8,7], exact: qh = 16*qhi+qlo
  int sh = 4 * (idx & 7);
  uint vlo = (uint)(qlo & 0xF) << sh;
  uint vhi = (uint)(qhi & 0xF) << sh;
  vlo |= __shfl_xor(vlo, 1); vhi |= __shfl_xor(vhi, 1);
  vlo |= __shfl_xor(vlo, 2); vhi |= __shfl_xor(vhi, 2);
  vlo |= __shfl_xor(vlo, 4); vhi |= __shfl_xor(vhi, 4);
  if ((idx & 7) == 0) {
    int g = idx >> 3;                       // word 0..31
    hp[(g >> 1) * 4 + (g & 1)] = vlo;       // .x/.y of uint4[g>>1]
    hp[(g >> 1) * 4 + 2 + (g & 1)] = vhi;   // .z/.w
  }
}

// One wave-row per matrix row: per-row absmax -> scale max/7, quantize to
// SIGNED 2's-complement nibbles. dst u16 layout per matrix (PAIRED):
// [bw2(8)][j(1024)][c(8)], u16 c holds nibbles k = 32*bw2 + 4*c .. +3
// (k ascending, low nibble first). Main loop reads uint4 tile[bw2*1024+j].
__global__ __launch_bounds__(64) void pack_q4w(const float* __restrict__ s0,
                                               const float* __restrict__ s1,
                                               const float* __restrict__ s2,
                                               ushort* __restrict__ dst,
                                               float* __restrict__ scl) {
  int r = blockIdx.x;                 // 0..3071
  int mat = r >> 10, j = r & 1023;
  int ln = threadIdx.x;               // 0..63, covers k = 4*ln..4*ln+3
  const float* src = (mat == 0 ? s0 : (mat == 1 ? s1 : s2)) + j * 256 + ln * 4;
  float4 v = *(const float4*)src;
  float m = fmaxf(fmaxf(fabsf(v.x), fabsf(v.y)), fmaxf(fabsf(v.z), fabsf(v.w)));
#pragma unroll
  for (int off = 32; off > 0; off >>= 1) m = fmaxf(m, __shfl_xor(m, off));
  float rcp = (m > 0.f) ? 7.0f / m : 0.f;
  int q0 = __float2int_rn(v.x * rcp);
  int q1 = __float2int_rn(v.y * rcp);
  int q2 = __float2int_rn(v.z * rcp);
  int q3 = __float2int_rn(v.w * rcp);
  uint p = (uint)(q0 & 0xF) | ((uint)(q1 & 0xF) << 4) |
           ((uint)(q2 & 0xF) << 8) | ((uint)(q3 & 0xF) << 12);
  dst[mat * 65536 + (ln >> 3) * 8192 + j * 8 + (ln & 7)] = (ushort)p;
  if (ln == 0) scl[mat * 1024 + j] = m * (1.0f / 7.0f);
}

__global__ __launch_bounds__(1024) void decoder_i4w(
    const float* __restrict__ seq, const float* __restrict__ z,
    const float* __restrict__ wih0, const float* __restrict__ bih0,
    const float* __restrict__ bhh0, const float* __restrict__ bih1,
    const float* __restrict__ bhh1, const float* __restrict__ wout,
    const float* __restrict__ bout, const uint4* __restrict__ w0,
    const uint4* __restrict__ w1i, const uint4* __restrict__ w1h,
    const float* __restrict__ scl, float* __restrict__ loss_out) {
  extern __shared__ uint4 lw4[];                  // whole whh0, i4 (128 KB)
  __shared__ alignas(16) uint4 h0p[kBW];          // h0 fused nibble planes
  __shared__ alignas(16) uint4 h1p[kBW];          // h1 fused nibble planes
  __shared__ float g4[1024];
  __shared__ float spred[kH];

  const int tid = threadIdx.x;                    // gate row j
  const int b = blockIdx.x;                       // batch element

  // Stage ALL of whh0 (i4) into LDS: 8192 uint4, coalesced.
#pragma unroll
  for (int i = 0; i < 8; ++i) lw4[i * 1024 + tid] = w0[i * 1024 + tid];

  float c0 = 0.f, c1 = 0.f, woutr = 0.f, zv = 0.f;
  if (tid < kH) {
    zv = z[(size_t)b * kH + tid];
    c0 = zv;
    c1 = zv;
    woutr = wout[tid];
    spred[tid] = fabsf(zv);                       // scratch for init max
  }
  const float wih0_j = wih0[tid];
  const float bias0 = bih0[tid] + bhh0[tid];
  const float bias1 = bih1[tid] + bhh1[tid];
  const float s0j = scl[tid];
  const float s1ij = scl[1024 + tid];
  const float s1hj = scl[2048 + tid];
  const float bo = bout[0];
  const bool isG = (tid >= 512) && (tid < 768);   // wave-uniform (waves 8..11)
  const float r119 = 1.0f / 119.0f;
  float xsv = 0.f, lacc = 0.f;
  __syncthreads();

  // Per-block max|z| (wave-redundant), init scale, quantize z into planes.
  float s_init;
  {
    int ln = tid & 63;
    float mm = fmaxf(fmaxf(spred[ln], spred[ln + 64]),
                     fmaxf(spred[ln + 128], spred[ln + 192]));
#pragma unroll
    for (int off = 32; off > 0; off >>= 1) mm = fmaxf(mm, __shfl_xor(mm, off));
    float m = fmaxf(mm, 1e-20f);
    s_init = m * r119;                            // qh = z / s_init
    if (tid < kH) {
      int q = __float2int_rn(zv * (119.0f / m));
      q = max(-119, min(119, q));
      pack_h((uint*)h0p, tid, q);
      pack_h((uint*)h1p, tid, q);
    }
  }

  const uint4* wpA = w1i + tid;
  const uint4* wpB = w1h + tid;
  const uint4* lwp = lw4 + tid;
  __syncthreads();

  for (int t = 0; t < kT; ++t) {
    // LICM fence (round-5 post-mortem: hoist->spill->scratch-bound).
    asm volatile("" ::: "memory");
    const float hs_old = (t == 0) ? s_init : r119;  // scale of h written t-1

    // ---- phase 1 (merged): D0 = Whh0.qh0 from LDS (pure VALU)
    //      interleaved with Dh = Whh1.qh1_old streamed (16B/lane loads).
    int D0l = 0, D0h = 0, Dhl = 0, Dhh = 0;
#pragma unroll 4
    for (int bw2 = 0; bw2 < kBW2; ++bw2) {
      uint4 qB = wpB[(size_t)bw2 << 10];          // global, dep-free: pipelined
      uint4 wl = lwp[bw2 << 10];
      dotw(wl.x, wl.y, h0p[2 * bw2], D0l, D0h);
      dotw(wl.z, wl.w, h0p[2 * bw2 + 1], D0l, D0h);
      dotw(qB.x, qB.y, h1p[2 * bw2], Dhl, Dhh);
      dotw(qB.z, qB.w, h1p[2 * bw2 + 1], Dhl, Dhh);
    }
    float a0 = fmaf(xsv, wih0_j, bias0) +
               s0j * hs_old * (float)(16 * D0h + D0l);
    g4[tid] = isG ? tanh_fast(a0) : fsig(a0);
    __syncthreads();
    if (tid < kH) {
      float gi = g4[tid];
      float gf = g4[tid + 256];
      float gg = g4[tid + 512];
      float go = g4[tid + 768];
      c0 = fmaf(gf, c0, gi * gg);
      float hn = go * tanh_fast(c0);              // in (-1,1)
      pack_h((uint*)h0p, tid, __float2int_rn(hn * 119.0f));  // scale 1/119
    }
    __syncthreads();

    // ---- phase 2: Di = Wih1.qh0_new, streamed (16B/lane loads) ----
    int Dil = 0, Dih = 0;
#pragma unroll 4
    for (int bw2 = 0; bw2 < kBW2; ++bw2) {
      uint4 qA = wpA[(size_t)bw2 << 10];
      dotw(qA.x, qA.y, h0p[2 * bw2], Dil, Dih);
      dotw(qA.z, qA.w, h0p[2 * bw2 + 1], Dil, Dih);
    }
    float a1 = bias1 + s1ij * r119 * (float)(16 * Dih + Dil) +
               s1hj * hs_old * (float)(16 * Dhh + Dhl);
    g4[tid] = isG ? tanh_fast(a1) : fsig(a1);
    __syncthreads();
    if (tid < kH) {
      float gi = g4[tid];
      float gf = g4[tid + 256];
      float gg = g4[tid + 512];
      float go = g4[tid + 768];
      c1 = fmaf(gf, c1, gi * gg);
      float hn = go * tanh_fast(c1);              // fp32, pre-quantization
      pack_h((uint*)h1p, tid, __float2int_rn(hn * 119.0f));  // scale 1/119
      spred[tid] = hn * woutr;                    // pred path stays fp32
    }
    __syncthreads();

    // ---- pred reduce (redundant per wave) ----
    {
      int ln = tid & 63;
      float v = spred[ln] + spred[ln + 64] + spred[ln + 128] + spred[ln + 192];
#pragma unroll
      for (int off = 32; off > 0; off >>= 1) v += __shfl_down(v, off);
      float pred = __shfl(v, 0) + bo;             // broadcast within wave
      xsv = pred;                                 // feedback for next step
      if (tid == 0) {
        float d = seq[(size_t)b * kT + t] - pred;
        lacc = fmaf(d, d, lacc);
      }
    }
    // no barrier needed: next writers pass 2+ barriers first
  }

  if (tid == 0) atomicAdd(loss_out, lacc * (1.0f / ((float)kB * (float)kT)));
}

// ---------------- fallback (reads d_in directly, fp32) ---------------------
__global__ __launch_bounds__(1024) void decoder_fallback(
    const float* __restrict__ seq, const float* __restrict__ z,
    const float* __restrict__ wih0, const float* __restrict__ bih0,
    const float* __restrict__ bhh0, const float* __restrict__ whh0,
    const float* __restrict__ wih1, const float* __restrict__ whh1,
    const float* __restrict__ bih1, const float* __restrict__ bhh1,
    const float* __restrict__ wout, const float* __restrict__ bout,
    float* __restrict__ loss_out) {
  __shared__ float h0s[kH], h1s[kH], g4[1024];
  __shared__ float xs_s;
  const int tid = threadIdx.x;
  const int b = blockIdx.x;
  float c0r = 0.f, c1r = 0.f;
  if (tid < kH) {
    float zv = z[b * kH + tid];
    h0s[tid] = zv; h1s[tid] = zv; c0r = zv; c1r = zv;
  }
  if (tid == 0) xs_s = 0.f;
  const float wih0_j = wih0[tid];
  const float bias0_j = bih0[tid] + bhh0[tid];
  const float bias1_j = bih1[tid] + bhh1[tid];
  const float wout_r = (tid < kH) ? wout[tid] : 0.f;
  const float bo = bout[0];
  float lacc = 0.f;
  __syncthreads();
  for (int t = 0; t < kT; ++t) {
    float a0 = fmaf(xs_s, wih0_j, bias0_j);
    for (int k = 0; k < kH; ++k) a0 = fmaf(whh0[tid * kH + k], h0s[k], a0);
    g4[tid] = a0;
    __syncthreads();
    if (tid < kH) {
      float ig = fsig(g4[tid]), fg = fsig(g4[tid + 256]);
      float gg = tanhf(g4[tid + 512]), og = fsig(g4[tid + 768]);
      c0r = fmaf(fg, c0r, ig * gg);
      h0s[tid] = og * tanhf(c0r);
    }
    __syncthreads();
    float a1 = bias1_j;
    for (int k = 0; k < kH; ++k) a1 = fmaf(wih1[tid * kH + k], h0s[k], a1);
    for (int k = 0; k < kH; ++k) a1 = fmaf(whh1[tid * kH + k], h1s[k], a1);
    g4[tid] = a1;
    __syncthreads();
    if (tid < kH) {
      float ig = fsig(g4[tid]), fg = fsig(g4[tid + 256]);
      float gg = tanhf(g4[tid + 512]), og = fsig(g4[tid + 768]);
      c1r = fmaf(fg, c1r, ig * gg);
      float h1 = og * tanhf(c1r);
      h1s[tid] = h1;
      g4[tid] = h1 * wout_r;
    }
    __syncthreads();
    if (tid < 64) {
      float v = g4[tid] + g4[tid + 64] + g4[tid + 128] + g4[tid + 192];
#pragma unroll
      for (int off = 32; off > 0; off >>= 1) v += __shfl_down(v, off);
      if (tid == 0) {
        float pred = v + bo;
        float d = seq[b * kT + t] - pred;
        lacc = fmaf(d, d, lacc);
        xs_s = pred;
      }
    }
    __syncthreads();
  }
  if (tid == 0) atomicAdd(loss_out, lacc * (1.0f / (float)(kB * kT)));
}

}  // namespace

extern "C" void kernel_launch(void* const* d_in, const int* in_sizes, int n_in,
                              void* d_out, int out_size, void* d_ws, size_t ws_size,
                              hipStream_t stream) {
  const float* seq = (const float*)d_in[0];
  const float* z = (const float*)d_in[1];
  const float* wih0 = (const float*)d_in[3];
  const float* whh0 = (const float*)d_in[4];
  const float* bih0 = (const float*)d_in[5];
  const float* bhh0 = (const float*)d_in[6];
  const float* wih1 = (const float*)d_in[7];
  const float* whh1 = (const float*)d_in[8];
  const float* bih1 = (const float*)d_in[9];
  const float* bhh1 = (const float*)d_in[10];
  const float* wout = (const float*)d_in[11];
  const float* bout = (const float*)d_in[12];
  float* out = (float*)d_out;

  hipMemsetAsync(out, 0, sizeof(float), stream);

  if (ws_size >= kWsNeeded) {
    ushort* wq = (ushort*)d_ws;             // [3][65536] u16 of signed nibbles
    float* scl = (float*)((char*)d_ws + 3 * (size_t)65536 * 2);
    pack_q4w<<<3072, 64, 0, stream>>>(whh0, wih1, whh1, wq, scl);
    // 128KB dynamic LDS (whole whh0) also forces 1 block/CU -> 256 blocks
    // land on 256 distinct CUs (full machine).
    const uint4* wu = (const uint4*)wq;
    decoder_i4w<<<kB, 1024, 128 * 1024, stream>>>(
        seq, z, wih0, bih0, bhh0, bih1, bhh1, wout, bout, wu,
        wu + 8 * 1024, wu + 16 * 1024, scl, out);
  } else {
    decoder_fallback<<<kB, 1024, 0, stream>>>(seq, z, wih0, bih0, bhh0, whh0,
                                              wih1, whh1, bih1, bhh1, wout, bout,
                                              out);
  }
}